// Round 7
// baseline (242.092 us; speedup 1.0000x reference)
//
#include <hip/hip_runtime.h>
#include <hip/hip_bf16.h>

// Problem constants
#define NB   128     // frames
#define NP   4096    // points per frame
#define NGRP 16
#define C3   512

typedef __bf16 bf16x8 __attribute__((ext_vector_type(8)));
typedef __bf16 bf16x4 __attribute__((ext_vector_type(4)));
typedef float  f32x4  __attribute__((ext_vector_type(4)));

// ws layout (bytes) — all weights in MFMA A-fragment chunk order:
// chunk c holds A[m=l15][k=quad*8+j] as elem c*512 + lane*8 + j
#define WS_W1F_G 0        // 4 chunks (64ch x K32, k>=4 zero)
#define WS_W1F_L 4096
#define WS_W2F_G 8192     // 16 chunks (128ch x K64): c = mi*2 + ks
#define WS_W2F_L 24576
#define WS_W3F_G 40960    // 128 chunks (512ch x K128): c = (ch>>4)*4 + (k>>5)
#define WS_W3F_L 172032
#define WS_GMAX  303104   // [16][512] f32 (end 335872)

__global__ __launch_bounds__(256) void prep_kernel(
    const float* __restrict__ Wg1, const float* __restrict__ Wg2, const float* __restrict__ Wg3,
    const float* __restrict__ Wl1, const float* __restrict__ Wl2, const float* __restrict__ Wl3,
    float* __restrict__ out, char* __restrict__ ws) {
    const int t = blockIdx.x, tid = threadIdx.x;
    if (t >= 37) {   // zero local-z region of out (atomicMax target for half-frame merge)
        int base = (t - 37) * 8192 + tid;
        #pragma unroll
        for (int k = 0; k < 32; ++k) {
            int i = base + k * 256;
            out[(i >> 9) * (2 * C3) + C3 + (i & 511)] = 0.0f;
        }
        return;
    }
    if (t == 36) {   // W1 frags (both branches) + gmax zero
        float* gmax = (float*)(ws + WS_GMAX);
        #pragma unroll
        for (int k = 0; k < 32; ++k) gmax[k * 256 + tid] = 0.0f;
        int c = tid >> 6, lane = tid & 63;
        int ch = c * 16 + (lane & 15);
        int kb = (lane >> 4) * 8;
        bf16x8 pg, pl;
        #pragma unroll
        for (int j = 0; j < 8; ++j) {
            int k = kb + j;
            pg[j] = (k < 4) ? (__bf16)Wg1[k * 64 + ch] : (__bf16)0.0f;
            pl[j] = (k < 4) ? (__bf16)Wl1[k * 64 + ch] : (__bf16)0.0f;
        }
        *(bf16x8*)((__bf16*)(ws + WS_W1F_G) + c * 512 + lane * 8) = pg;
        *(bf16x8*)((__bf16*)(ws + WS_W1F_L) + c * 512 + lane * 8) = pl;
        return;
    }
    // W2/W3 transpose-to-fragment tiles via LDS (coalesced both sides)
    __shared__ float tile[64][65];
    const float* src; __bf16* dst; int cBase, mMul, srcStride;
    if (t < 32) {       // W3 [128k][512ch]: tiles 64x64, (tk 0..1, tc 0..7) per branch
        int branch = t >> 4, rem = t & 15;
        int tk = rem >> 3, tc = rem & 7;
        src = (branch ? Wl3 : Wg3) + (size_t)(tk * 64) * 512 + tc * 64;
        dst = (__bf16*)(ws + (branch ? WS_W3F_L : WS_W3F_G));
        cBase = tc * 16 + tk * 2; mMul = 4; srcStride = 512;
    } else {            // W2 [64k][128ch]: tiles 64x64, tc 0..1 per branch
        int u = t - 32; int branch = u >> 1, tc = u & 1;
        src = (branch ? Wl2 : Wg2) + tc * 64;
        dst = (__bf16*)(ws + (branch ? WS_W2F_L : WS_W2F_G));
        cBase = tc * 8; mMul = 2; srcStride = 128;
    }
    {
        int r0 = tid >> 6, cl = tid & 63;
        #pragma unroll
        for (int p = 0; p < 16; ++p)
            tile[p * 4 + r0][cl] = src[(size_t)(p * 4 + r0) * srcStride + cl];
    }
    __syncthreads();
    int lane = tid & 63, l15 = lane & 15, q = lane >> 4;
    #pragma unroll
    for (int cc = 0; cc < 2; ++cc) {
        int pair = (tid >> 6) * 2 + cc;     // (mi,ks) 0..7
        int mi = pair >> 1, ks = pair & 1;
        bf16x8 pk;
        #pragma unroll
        for (int j = 0; j < 8; ++j) pk[j] = (__bf16)tile[ks * 32 + q * 8 + j][mi * 16 + l15];
        *(bf16x8*)(dst + (cBase + mi * mMul + ks) * 512 + lane * 8) = pk;
    }
}

// Grid (128 frames, 2 branches, 2 half-frames) = 512 blocks of 512 threads.
// LDS single-buffered h2f -> 68096 B/block -> TWO blocks co-resident per CU
// (136 KB < 160 KB). launch_bounds(512,2) keeps the R6-verified 108-VGPR
// allocation (NOT (512,4), which forced the 64+64 split and spilled in R1);
// 108 VGPR quantizes to the 128-step -> 4 waves/SIMD permitted, so both
// blocks run: each SIMD hosts 2 waves of block A + 2 of block B with
// INDEPENDENT barriers. When A drains its per-macro barrier or runs the
// serial stage-C region, B's 16-MFMA ni-groups feed the matrix pipe
// (m114 cross-wave co-schedule) — de-phasing with zero added registers.
// Half-frame split (16 macros each): no work duplication. Per macro:
// {barrier: h2f ready; phase-2 ni loop with stages A@2/B@4 interleaved;
// barrier: reads done; stage C rewrites h2f}. Local-branch max merged
// across the two half-blocks via atomicMax into out (prep zeroes; relu>=0
// makes uint-compare max valid — same trick as gmax).
__global__ __launch_bounds__(512, 2) void main_kernel(
    const float* __restrict__ pc, const float* __restrict__ tt, const int* __restrict__ idx,
    const float* __restrict__ bg1, const float* __restrict__ bg2, const float* __restrict__ bg3,
    const float* __restrict__ bl1, const float* __restrict__ bl2, const float* __restrict__ bl3,
    float* __restrict__ out, char* __restrict__ ws) {
    __shared__ __align__(16) char smem[68096];
    __bf16* h2f = (__bf16*)smem;               // 16384 elems (32768 B), single buffer
    __bf16* w2f = (__bf16*)(smem + 32768);     // 8192 elems (16384 B)
    __bf16* h1s = (__bf16*)(smem + 49152);     // 8 waves x [16pt][72] (18432 B)
    float*  b2s = (float*)(smem + 67584);      // 128 f32 (512 B)

    const int tid = threadIdx.x, lane = tid & 63, wave = tid >> 6;
    const int quad = lane >> 4, l15 = lane & 15;
    const int branch = blockIdx.y, frame = blockIdx.x, hblk = blockIdx.z;

    const __bf16* w1g = (const __bf16*)(ws + (branch ? WS_W1F_L : WS_W1F_G));
    const __bf16* w2g = (const __bf16*)(ws + (branch ? WS_W2F_L : WS_W2F_G));
    const __bf16* w3g = (const __bf16*)(ws + (branch ? WS_W3F_L : WS_W3F_G));
    const float* b1 = branch ? bl1 : bg1;
    const float* b2 = branch ? bl2 : bg2;
    const float* b3 = branch ? bl3 : bg3;

    // stage W2 frags + b2 into LDS
    for (int i = tid; i < 1024; i += 512) ((f32x4*)w2f)[i] = ((const f32x4*)w2g)[i];
    if (tid < 128) b2s[tid] = b2[tid];

    // resident frags: W1 (16 VGPR), W3 slice (64 VGPR)
    bf16x8 a1[4];
    #pragma unroll
    for (int mi = 0; mi < 4; ++mi) a1[mi] = *(const bf16x8*)(w1g + mi * 512 + lane * 8);
    bf16x8 aw[4][4];
    #pragma unroll
    for (int mi = 0; mi < 4; ++mi)
        #pragma unroll
        for (int ks = 0; ks < 4; ++ks)
            aw[mi][ks] = *(const bf16x8*)(w3g + (wave * 16 + mi * 4 + ks) * 512 + lane * 8);

    float b1r[4][4];
    #pragma unroll
    for (int mi = 0; mi < 4; ++mi)
        #pragma unroll
        for (int r = 0; r < 4; ++r) b1r[mi][r] = b1[mi * 16 + quad * 4 + r];

    const float tval = tt[frame];
    const f32x4 zf = {0.0f, 0.0f, 0.0f, 0.0f};
    f32x4 runmax[4];
    #pragma unroll
    for (int mi = 0; mi < 4; ++mi) runmax[mi] = (f32x4){-1e30f, -1e30f, -1e30f, -1e30f};

    const float* pcx = pc + (size_t)frame * 3 * NP;
    __bf16* hs = h1s + wave * 1152;      // private [16][72] scratch
    const int pw = wave * 16 + l15;      // this wave's point (col l15) in a macro
    const int pbase = hblk * 2048;       // this block's half-frame point base

    // macro-0 x
    float xx = pcx[pbase + pw], xy = pcx[NP + pbase + pw], xz = pcx[2 * NP + pbase + pw];

    __syncthreads();   // w2f/b2s ready

    // ---- prologue: P1(0) -> h2f
    {
        bf16x8 xb;
        #pragma unroll
        for (int j = 0; j < 8; ++j) xb[j] = (__bf16)0.0f;
        if (quad == 0) { xb[0] = (__bf16)xx; xb[1] = (__bf16)xy; xb[2] = (__bf16)xz; xb[3] = (__bf16)tval; }
        #pragma unroll
        for (int mi = 0; mi < 4; ++mi) {
            f32x4 c = __builtin_amdgcn_mfma_f32_16x16x32_bf16(a1[mi], xb, zf, 0, 0, 0);
            bf16x4 pk;
            #pragma unroll
            for (int r = 0; r < 4; ++r) pk[r] = (__bf16)fmaxf(c[r] + b1r[mi][r], 0.0f);
            *(bf16x4*)(hs + l15 * 72 + mi * 16 + quad * 4) = pk;
        }
        bf16x8 hbf0 = *(const bf16x8*)(hs + l15 * 72 + quad * 8);
        bf16x8 hbf1 = *(const bf16x8*)(hs + l15 * 72 + 32 + quad * 8);
        #pragma unroll
        for (int mi = 0; mi < 8; ++mi) {
            bf16x8 a20 = *(const bf16x8*)(w2f + (mi * 2) * 512 + lane * 8);
            bf16x8 a21 = *(const bf16x8*)(w2f + (mi * 2 + 1) * 512 + lane * 8);
            f32x4 c = __builtin_amdgcn_mfma_f32_16x16x32_bf16(a20, hbf0, zf, 0, 0, 0);
            c = __builtin_amdgcn_mfma_f32_16x16x32_bf16(a21, hbf1, c, 0, 0, 0);
            f32x4 bb = *(const f32x4*)(b2s + mi * 16 + quad * 4);
            bf16x4 pk;
            #pragma unroll
            for (int r = 0; r < 4; ++r) pk[r] = (__bf16)fmaxf(c[r] + bb[r], 0.0f);
            const int c0 = mi * 16 + quad * 4;
            *(bf16x4*)(h2f + ((wave * 4 + (c0 >> 5)) * 4 + ((c0 >> 3) & 3)) * 128 + l15 * 8 + (c0 & 7)) = pk;
        }
    }

    for (int m = 0; m < 16; ++m) {
        __syncthreads();   // h2f(m) ready (prologue or previous stage C)
        const bool more = (m < 15);
        // prefetch next macro's x early (covered by >=2 ni-groups of MFMA)
        float nx = 0.f, ny = 0.f, nz = 0.f;
        if (more) {
            const int p = pbase + (m + 1) * 128 + pw;
            nx = pcx[p]; ny = pcx[NP + p]; nz = pcx[2 * NP + p];
        }
        bf16x8 hbf0, hbf1;
        bf16x8 bh0[4], bh1[4];
        #pragma unroll
        for (int ks = 0; ks < 4; ++ks) bh0[ks] = *(const bf16x8*)(h2f + ks * 512 + lane * 8);
        #pragma unroll
        for (int ni = 0; ni < 8; ++ni) {
            bf16x8* cur = (ni & 1) ? bh1 : bh0;
            bf16x8* nxt = (ni & 1) ? bh0 : bh1;
            if (ni < 7) {
                #pragma unroll
                for (int ks = 0; ks < 4; ++ks)
                    nxt[ks] = *(const bf16x8*)(h2f + ((ni + 1) * 4 + ks) * 512 + lane * 8);
            }
            f32x4 acc[4];
            #pragma unroll
            for (int ks = 0; ks < 4; ++ks)
                #pragma unroll
                for (int mi = 0; mi < 4; ++mi)
                    acc[mi] = __builtin_amdgcn_mfma_f32_16x16x32_bf16(
                        aw[mi][ks], cur[ks], ks ? acc[mi] : zf, 0, 0, 0);
            #pragma unroll
            for (int mi = 0; mi < 4; ++mi)
                #pragma unroll
                for (int r = 0; r < 4; ++r)
                    runmax[mi][r] = fmaxf(runmax[mi][r], acc[mi][r]);

            if (more && ni == 2) {   // P1 stage A: L1 of macro m+1, private scratch
                bf16x8 xb;
                #pragma unroll
                for (int j = 0; j < 8; ++j) xb[j] = (__bf16)0.0f;
                if (quad == 0) { xb[0] = (__bf16)nx; xb[1] = (__bf16)ny; xb[2] = (__bf16)nz; xb[3] = (__bf16)tval; }
                #pragma unroll
                for (int mi = 0; mi < 4; ++mi) {
                    f32x4 c = __builtin_amdgcn_mfma_f32_16x16x32_bf16(a1[mi], xb, zf, 0, 0, 0);
                    bf16x4 pk;
                    #pragma unroll
                    for (int r = 0; r < 4; ++r) pk[r] = (__bf16)fmaxf(c[r] + b1r[mi][r], 0.0f);
                    *(bf16x4*)(hs + l15 * 72 + mi * 16 + quad * 4) = pk;
                }
            }
            if (more && ni == 4) {   // stage B: C->B transform readback
                hbf0 = *(const bf16x8*)(hs + l15 * 72 + quad * 8);
                hbf1 = *(const bf16x8*)(hs + l15 * 72 + 32 + quad * 8);
            }
        }
        __syncthreads();   // all phase-2 reads of h2f(m) done
        if (more) {        // stage C: L2 -> rewrite h2f with macro m+1
            #pragma unroll
            for (int mi = 0; mi < 8; ++mi) {
                bf16x8 a20 = *(const bf16x8*)(w2f + (mi * 2) * 512 + lane * 8);
                bf16x8 a21 = *(const bf16x8*)(w2f + (mi * 2 + 1) * 512 + lane * 8);
                f32x4 c = __builtin_amdgcn_mfma_f32_16x16x32_bf16(a20, hbf0, zf, 0, 0, 0);
                c = __builtin_amdgcn_mfma_f32_16x16x32_bf16(a21, hbf1, c, 0, 0, 0);
                f32x4 bb = *(const f32x4*)(b2s + mi * 16 + quad * 4);
                bf16x4 pk;
                #pragma unroll
                for (int r = 0; r < 4; ++r) pk[r] = (__bf16)fmaxf(c[r] + bb[r], 0.0f);
                const int c0 = mi * 16 + quad * 4;
                *(bf16x4*)(h2f + ((wave * 4 + (c0 >> 5)) * 4 + ((c0 >> 3) & 3)) * 128 + l15 * 8 + (c0 & 7)) = pk;
            }
        }
    }

    // ---- finalize: fold 16 point-columns, bias3+relu, atomic-merge
    const int g = idx[frame];
    float* gmax = (float*)(ws + WS_GMAX);
    #pragma unroll
    for (int mi = 0; mi < 4; ++mi) {
        f32x4 v = runmax[mi];
        #pragma unroll
        for (int d = 1; d < 16; d <<= 1) {
            #pragma unroll
            for (int r = 0; r < 4; ++r) v[r] = fmaxf(v[r], __shfl_xor(v[r], d));
        }
        if (l15 == 0) {
            #pragma unroll
            for (int r = 0; r < 4; ++r) {
                const int ch = wave * 64 + mi * 16 + quad * 4 + r;
                const float fv = fmaxf(v[r] + b3[ch], 0.0f);
                if (branch == 0)
                    atomicMax((unsigned*)(gmax + g * C3 + ch), __float_as_uint(fv)); // relu>=0
                else
                    atomicMax((unsigned*)(out + (size_t)frame * (2 * C3) + C3 + ch),
                              __float_as_uint(fv));   // merge the two half-frame blocks
            }
        }
    }
}

__global__ void gather_kernel(const int* __restrict__ idx, const char* __restrict__ ws,
                              const float* __restrict__ pc, float* __restrict__ out) {
    int i = blockIdx.x * blockDim.x + threadIdx.x;   // 0..65535
    int b = i >> 9, ch = i & 511;
    const float* gmax = (const float*)(ws + WS_GMAX);
    out[b * (2 * C3) + ch] = gmax[idx[b] * C3 + ch];
    // pc passthrough (off the prep->main critical path): 393216 float4
    const f32x4* src = (const f32x4*)pc;
    f32x4* dst = (f32x4*)(out + NB * 2 * C3);
    #pragma unroll
    for (int j = 0; j < 6; ++j) dst[i + j * 65536] = src[i + j * 65536];
}

extern "C" void kernel_launch(void* const* d_in, const int* in_sizes, int n_in,
                              void* d_out, int out_size, void* d_ws, size_t ws_size,
                              hipStream_t stream) {
    const float* pc  = (const float*)d_in[0];
    const float* tt  = (const float*)d_in[1];
    const int*   idx = (const int*)d_in[2];
    const float* Wg1 = (const float*)d_in[3];  const float* bg1 = (const float*)d_in[4];
    const float* Wg2 = (const float*)d_in[5];  const float* bg2 = (const float*)d_in[6];
    const float* Wg3 = (const float*)d_in[7];  const float* bg3 = (const float*)d_in[8];
    const float* Wl1 = (const float*)d_in[9];  const float* bl1 = (const float*)d_in[10];
    const float* Wl2 = (const float*)d_in[11]; const float* bl2 = (const float*)d_in[12];
    const float* Wl3 = (const float*)d_in[13]; const float* bl3 = (const float*)d_in[14];
    float* out = (float*)d_out;
    char*  ws  = (char*)d_ws;

    // prep: weight frag layout (LDS transpose), gmax zero, local-z zero
    prep_kernel<<<45, 256, 0, stream>>>(Wg1, Wg2, Wg3, Wl1, Wl2, Wl3, out, ws);
    // main: 128 frames x 2 branches x 2 half-frames = 512 blocks = 2 per CU
    main_kernel<<<dim3(128, 2, 2), 512, 0, stream>>>(pc, tt, idx, bg1, bg2, bg3,
                                                     bl1, bl2, bl3, out, ws);
    gather_kernel<<<256, 256, 0, stream>>>(idx, ws, pc, out);
}

// Round 8
// 238.853 us; speedup vs baseline: 1.0136x; 1.0136x over previous
//
#include <hip/hip_runtime.h>
#include <hip/hip_bf16.h>

// Problem constants
#define NB   128     // frames
#define NP   4096    // points per frame
#define NGRP 16
#define C3   512

typedef __bf16 bf16x8 __attribute__((ext_vector_type(8)));
typedef __bf16 bf16x4 __attribute__((ext_vector_type(4)));
typedef float  f32x4  __attribute__((ext_vector_type(4)));

// ws layout (bytes) — all weights in MFMA A-fragment chunk order:
// chunk c holds A[m=l15][k=quad*8+j] as elem c*512 + lane*8 + j
#define WS_W1F_G 0        // 4 chunks (64ch x K32, k>=4 zero)
#define WS_W1F_L 4096
#define WS_W2F_G 8192     // 16 chunks (128ch x K64): c = mi*2 + ks
#define WS_W2F_L 24576
#define WS_W3F_G 40960    // 128 chunks (512ch x K128): c = (ch>>4)*4 + (k>>5)
#define WS_W3F_L 172032
#define WS_GMAX  303104   // [16][512] f32 (end 335872)

__global__ __launch_bounds__(256) void prep_kernel(
    const float* __restrict__ Wg1, const float* __restrict__ Wg2, const float* __restrict__ Wg3,
    const float* __restrict__ Wl1, const float* __restrict__ Wl2, const float* __restrict__ Wl3,
    float* __restrict__ out, char* __restrict__ ws) {
    const int t = blockIdx.x, tid = threadIdx.x;
    if (t >= 37) {   // zero local-z region of out (atomicMax target for half-frame merge)
        int base = (t - 37) * 8192 + tid;
        #pragma unroll
        for (int k = 0; k < 32; ++k) {
            int i = base + k * 256;
            out[(i >> 9) * (2 * C3) + C3 + (i & 511)] = 0.0f;
        }
        return;
    }
    if (t == 36) {   // W1 frags (both branches) + gmax zero
        float* gmax = (float*)(ws + WS_GMAX);
        #pragma unroll
        for (int k = 0; k < 32; ++k) gmax[k * 256 + tid] = 0.0f;
        int c = tid >> 6, lane = tid & 63;
        int ch = c * 16 + (lane & 15);
        int kb = (lane >> 4) * 8;
        bf16x8 pg, pl;
        #pragma unroll
        for (int j = 0; j < 8; ++j) {
            int k = kb + j;
            pg[j] = (k < 4) ? (__bf16)Wg1[k * 64 + ch] : (__bf16)0.0f;
            pl[j] = (k < 4) ? (__bf16)Wl1[k * 64 + ch] : (__bf16)0.0f;
        }
        *(bf16x8*)((__bf16*)(ws + WS_W1F_G) + c * 512 + lane * 8) = pg;
        *(bf16x8*)((__bf16*)(ws + WS_W1F_L) + c * 512 + lane * 8) = pl;
        return;
    }
    // W2/W3 transpose-to-fragment tiles via LDS (coalesced both sides)
    __shared__ float tile[64][65];
    const float* src; __bf16* dst; int cBase, mMul, srcStride;
    if (t < 32) {       // W3 [128k][512ch]: tiles 64x64, (tk 0..1, tc 0..7) per branch
        int branch = t >> 4, rem = t & 15;
        int tk = rem >> 3, tc = rem & 7;
        src = (branch ? Wl3 : Wg3) + (size_t)(tk * 64) * 512 + tc * 64;
        dst = (__bf16*)(ws + (branch ? WS_W3F_L : WS_W3F_G));
        cBase = tc * 16 + tk * 2; mMul = 4; srcStride = 512;
    } else {            // W2 [64k][128ch]: tiles 64x64, tc 0..1 per branch
        int u = t - 32; int branch = u >> 1, tc = u & 1;
        src = (branch ? Wl2 : Wg2) + tc * 64;
        dst = (__bf16*)(ws + (branch ? WS_W2F_L : WS_W2F_G));
        cBase = tc * 8; mMul = 2; srcStride = 128;
    }
    {
        int r0 = tid >> 6, cl = tid & 63;
        #pragma unroll
        for (int p = 0; p < 16; ++p)
            tile[p * 4 + r0][cl] = src[(size_t)(p * 4 + r0) * srcStride + cl];
    }
    __syncthreads();
    int lane = tid & 63, l15 = lane & 15, q = lane >> 4;
    #pragma unroll
    for (int cc = 0; cc < 2; ++cc) {
        int pair = (tid >> 6) * 2 + cc;     // (mi,ks) 0..7
        int mi = pair >> 1, ks = pair & 1;
        bf16x8 pk;
        #pragma unroll
        for (int j = 0; j < 8; ++j) pk[j] = (__bf16)tile[ks * 32 + q * 8 + j][mi * 16 + l15];
        *(bf16x8*)(dst + (cBase + mi * mMul + ks) * 512 + lane * 8) = pk;
    }
}

// Grid (128 frames, 2 branches, 2 half-frames) = 512 blocks of 512 threads.
// Single-buffered h2f -> LDS 68096 B -> TWO blocks co-resident per CU.
// launch_bounds(512,2) = 256-reg budget (R6's 108-VGPR config). R7's spill
// cause removed: stage B (hbf readback at ni=4) is DELETED — stage C reads
// hbf from the wave-private hs scratch AFTER the second barrier (hs persists
// in LDS; no cross-barrier register liveness). Each SIMD then hosts 2 waves
// of block A + 2 of block B with independent barriers: when A drains its
// barrier or runs serial stage C, B's 16-MFMA ni-groups feed the matrix
// pipe (m114 co-schedule) — de-phasing with zero added live registers.
// Half-frame split (16 macros each): no work duplication. Local-branch max
// merged across the two half-blocks via atomicMax into out (prep zeroes;
// relu >= 0 makes uint-compare max valid — same trick as gmax).
__global__ __launch_bounds__(512, 2) void main_kernel(
    const float* __restrict__ pc, const float* __restrict__ tt, const int* __restrict__ idx,
    const float* __restrict__ bg1, const float* __restrict__ bg2, const float* __restrict__ bg3,
    const float* __restrict__ bl1, const float* __restrict__ bl2, const float* __restrict__ bl3,
    float* __restrict__ out, char* __restrict__ ws) {
    __shared__ __align__(16) char smem[68096];
    __bf16* h2f = (__bf16*)smem;               // 16384 elems (32768 B), single buffer
    __bf16* w2f = (__bf16*)(smem + 32768);     // 8192 elems (16384 B)
    __bf16* h1s = (__bf16*)(smem + 49152);     // 8 waves x [16pt][72] (18432 B)
    float*  b2s = (float*)(smem + 67584);      // 128 f32 (512 B)

    const int tid = threadIdx.x, lane = tid & 63, wave = tid >> 6;
    const int quad = lane >> 4, l15 = lane & 15;
    const int branch = blockIdx.y, frame = blockIdx.x, hblk = blockIdx.z;

    const __bf16* w1g = (const __bf16*)(ws + (branch ? WS_W1F_L : WS_W1F_G));
    const __bf16* w2g = (const __bf16*)(ws + (branch ? WS_W2F_L : WS_W2F_G));
    const __bf16* w3g = (const __bf16*)(ws + (branch ? WS_W3F_L : WS_W3F_G));
    const float* b1 = branch ? bl1 : bg1;
    const float* b2 = branch ? bl2 : bg2;
    const float* b3 = branch ? bl3 : bg3;

    // stage W2 frags + b2 into LDS
    for (int i = tid; i < 1024; i += 512) ((f32x4*)w2f)[i] = ((const f32x4*)w2g)[i];
    if (tid < 128) b2s[tid] = b2[tid];

    // resident frags: W1 (16 VGPR), W3 slice (64 VGPR)
    bf16x8 a1[4];
    #pragma unroll
    for (int mi = 0; mi < 4; ++mi) a1[mi] = *(const bf16x8*)(w1g + mi * 512 + lane * 8);
    bf16x8 aw[4][4];
    #pragma unroll
    for (int mi = 0; mi < 4; ++mi)
        #pragma unroll
        for (int ks = 0; ks < 4; ++ks)
            aw[mi][ks] = *(const bf16x8*)(w3g + (wave * 16 + mi * 4 + ks) * 512 + lane * 8);

    float b1r[4][4];
    #pragma unroll
    for (int mi = 0; mi < 4; ++mi)
        #pragma unroll
        for (int r = 0; r < 4; ++r) b1r[mi][r] = b1[mi * 16 + quad * 4 + r];

    const float tval = tt[frame];
    const f32x4 zf = {0.0f, 0.0f, 0.0f, 0.0f};
    f32x4 runmax[4];
    #pragma unroll
    for (int mi = 0; mi < 4; ++mi) runmax[mi] = (f32x4){-1e30f, -1e30f, -1e30f, -1e30f};

    const float* pcx = pc + (size_t)frame * 3 * NP;
    __bf16* hs = h1s + wave * 1152;      // private [16][72] scratch
    const int pw = wave * 16 + l15;      // this wave's point (col l15) in a macro
    const int pbase = hblk * 2048;       // this block's half-frame point base

    // macro-0 x
    float xx = pcx[pbase + pw], xy = pcx[NP + pbase + pw], xz = pcx[2 * NP + pbase + pw];

    __syncthreads();   // w2f/b2s ready

    // ---- prologue: P1(0) -> h2f
    {
        bf16x8 xb;
        #pragma unroll
        for (int j = 0; j < 8; ++j) xb[j] = (__bf16)0.0f;
        if (quad == 0) { xb[0] = (__bf16)xx; xb[1] = (__bf16)xy; xb[2] = (__bf16)xz; xb[3] = (__bf16)tval; }
        #pragma unroll
        for (int mi = 0; mi < 4; ++mi) {
            f32x4 c = __builtin_amdgcn_mfma_f32_16x16x32_bf16(a1[mi], xb, zf, 0, 0, 0);
            bf16x4 pk;
            #pragma unroll
            for (int r = 0; r < 4; ++r) pk[r] = (__bf16)fmaxf(c[r] + b1r[mi][r], 0.0f);
            *(bf16x4*)(hs + l15 * 72 + mi * 16 + quad * 4) = pk;
        }
        bf16x8 hbf0 = *(const bf16x8*)(hs + l15 * 72 + quad * 8);
        bf16x8 hbf1 = *(const bf16x8*)(hs + l15 * 72 + 32 + quad * 8);
        #pragma unroll
        for (int mi = 0; mi < 8; ++mi) {
            bf16x8 a20 = *(const bf16x8*)(w2f + (mi * 2) * 512 + lane * 8);
            bf16x8 a21 = *(const bf16x8*)(w2f + (mi * 2 + 1) * 512 + lane * 8);
            f32x4 c = __builtin_amdgcn_mfma_f32_16x16x32_bf16(a20, hbf0, zf, 0, 0, 0);
            c = __builtin_amdgcn_mfma_f32_16x16x32_bf16(a21, hbf1, c, 0, 0, 0);
            f32x4 bb = *(const f32x4*)(b2s + mi * 16 + quad * 4);
            bf16x4 pk;
            #pragma unroll
            for (int r = 0; r < 4; ++r) pk[r] = (__bf16)fmaxf(c[r] + bb[r], 0.0f);
            const int c0 = mi * 16 + quad * 4;
            *(bf16x4*)(h2f + ((wave * 4 + (c0 >> 5)) * 4 + ((c0 >> 3) & 3)) * 128 + l15 * 8 + (c0 & 7)) = pk;
        }
    }

    for (int m = 0; m < 16; ++m) {
        __syncthreads();   // h2f(m) ready (prologue or previous stage C)
        const bool more = (m < 15);
        // prefetch next macro's x early (covered by >=2 ni-groups of MFMA)
        float nx = 0.f, ny = 0.f, nz = 0.f;
        if (more) {
            const int p = pbase + (m + 1) * 128 + pw;
            nx = pcx[p]; ny = pcx[NP + p]; nz = pcx[2 * NP + p];
        }
        bf16x8 bh0[4], bh1[4];
        #pragma unroll
        for (int ks = 0; ks < 4; ++ks) bh0[ks] = *(const bf16x8*)(h2f + ks * 512 + lane * 8);
        #pragma unroll
        for (int ni = 0; ni < 8; ++ni) {
            bf16x8* cur = (ni & 1) ? bh1 : bh0;
            bf16x8* nxt = (ni & 1) ? bh0 : bh1;
            if (ni < 7) {
                #pragma unroll
                for (int ks = 0; ks < 4; ++ks)
                    nxt[ks] = *(const bf16x8*)(h2f + ((ni + 1) * 4 + ks) * 512 + lane * 8);
            }
            f32x4 acc[4];
            #pragma unroll
            for (int ks = 0; ks < 4; ++ks)
                #pragma unroll
                for (int mi = 0; mi < 4; ++mi)
                    acc[mi] = __builtin_amdgcn_mfma_f32_16x16x32_bf16(
                        aw[mi][ks], cur[ks], ks ? acc[mi] : zf, 0, 0, 0);
            #pragma unroll
            for (int mi = 0; mi < 4; ++mi)
                #pragma unroll
                for (int r = 0; r < 4; ++r)
                    runmax[mi][r] = fmaxf(runmax[mi][r], acc[mi][r]);

            if (more && ni == 2) {   // P1 stage A: L1 of macro m+1, private scratch
                bf16x8 xb;
                #pragma unroll
                for (int j = 0; j < 8; ++j) xb[j] = (__bf16)0.0f;
                if (quad == 0) { xb[0] = (__bf16)nx; xb[1] = (__bf16)ny; xb[2] = (__bf16)nz; xb[3] = (__bf16)tval; }
                #pragma unroll
                for (int mi = 0; mi < 4; ++mi) {
                    f32x4 c = __builtin_amdgcn_mfma_f32_16x16x32_bf16(a1[mi], xb, zf, 0, 0, 0);
                    bf16x4 pk;
                    #pragma unroll
                    for (int r = 0; r < 4; ++r) pk[r] = (__bf16)fmaxf(c[r] + b1r[mi][r], 0.0f);
                    *(bf16x4*)(hs + l15 * 72 + mi * 16 + quad * 4) = pk;
                }
            }
        }
        __syncthreads();   // all phase-2 reads of h2f(m) done
        if (more) {        // stage C: read hbf from hs (post-barrier, no reg
                           // carried across the barrier), L2 -> rewrite h2f
            bf16x8 hbf0 = *(const bf16x8*)(hs + l15 * 72 + quad * 8);
            bf16x8 hbf1 = *(const bf16x8*)(hs + l15 * 72 + 32 + quad * 8);
            #pragma unroll
            for (int mi = 0; mi < 8; ++mi) {
                bf16x8 a20 = *(const bf16x8*)(w2f + (mi * 2) * 512 + lane * 8);
                bf16x8 a21 = *(const bf16x8*)(w2f + (mi * 2 + 1) * 512 + lane * 8);
                f32x4 c = __builtin_amdgcn_mfma_f32_16x16x32_bf16(a20, hbf0, zf, 0, 0, 0);
                c = __builtin_amdgcn_mfma_f32_16x16x32_bf16(a21, hbf1, c, 0, 0, 0);
                f32x4 bb = *(const f32x4*)(b2s + mi * 16 + quad * 4);
                bf16x4 pk;
                #pragma unroll
                for (int r = 0; r < 4; ++r) pk[r] = (__bf16)fmaxf(c[r] + bb[r], 0.0f);
                const int c0 = mi * 16 + quad * 4;
                *(bf16x4*)(h2f + ((wave * 4 + (c0 >> 5)) * 4 + ((c0 >> 3) & 3)) * 128 + l15 * 8 + (c0 & 7)) = pk;
            }
        }
    }

    // ---- finalize: fold 16 point-columns, bias3+relu, atomic-merge
    const int g = idx[frame];
    float* gmax = (float*)(ws + WS_GMAX);
    #pragma unroll
    for (int mi = 0; mi < 4; ++mi) {
        f32x4 v = runmax[mi];
        #pragma unroll
        for (int d = 1; d < 16; d <<= 1) {
            #pragma unroll
            for (int r = 0; r < 4; ++r) v[r] = fmaxf(v[r], __shfl_xor(v[r], d));
        }
        if (l15 == 0) {
            #pragma unroll
            for (int r = 0; r < 4; ++r) {
                const int ch = wave * 64 + mi * 16 + quad * 4 + r;
                const float fv = fmaxf(v[r] + b3[ch], 0.0f);
                if (branch == 0)
                    atomicMax((unsigned*)(gmax + g * C3 + ch), __float_as_uint(fv)); // relu>=0
                else
                    atomicMax((unsigned*)(out + (size_t)frame * (2 * C3) + C3 + ch),
                              __float_as_uint(fv));   // merge the two half-frame blocks
            }
        }
    }
}

__global__ void gather_kernel(const int* __restrict__ idx, const char* __restrict__ ws,
                              const float* __restrict__ pc, float* __restrict__ out) {
    int i = blockIdx.x * blockDim.x + threadIdx.x;   // 0..65535
    int b = i >> 9, ch = i & 511;
    const float* gmax = (const float*)(ws + WS_GMAX);
    out[b * (2 * C3) + ch] = gmax[idx[b] * C3 + ch];
    // pc passthrough (off the prep->main critical path): 393216 float4
    const f32x4* src = (const f32x4*)pc;
    f32x4* dst = (f32x4*)(out + NB * 2 * C3);
    #pragma unroll
    for (int j = 0; j < 6; ++j) dst[i + j * 65536] = src[i + j * 65536];
}

extern "C" void kernel_launch(void* const* d_in, const int* in_sizes, int n_in,
                              void* d_out, int out_size, void* d_ws, size_t ws_size,
                              hipStream_t stream) {
    const float* pc  = (const float*)d_in[0];
    const float* tt  = (const float*)d_in[1];
    const int*   idx = (const int*)d_in[2];
    const float* Wg1 = (const float*)d_in[3];  const float* bg1 = (const float*)d_in[4];
    const float* Wg2 = (const float*)d_in[5];  const float* bg2 = (const float*)d_in[6];
    const float* Wg3 = (const float*)d_in[7];  const float* bg3 = (const float*)d_in[8];
    const float* Wl1 = (const float*)d_in[9];  const float* bl1 = (const float*)d_in[10];
    const float* Wl2 = (const float*)d_in[11]; const float* bl2 = (const float*)d_in[12];
    const float* Wl3 = (const float*)d_in[13]; const float* bl3 = (const float*)d_in[14];
    float* out = (float*)d_out;
    char*  ws  = (char*)d_ws;

    // prep: weight frag layout (LDS transpose), gmax zero, local-z zero
    prep_kernel<<<45, 256, 0, stream>>>(Wg1, Wg2, Wg3, Wl1, Wl2, Wl3, out, ws);
    // main: 128 frames x 2 branches x 2 half-frames = 512 blocks = 2 per CU
    main_kernel<<<dim3(128, 2, 2), 512, 0, stream>>>(pc, tt, idx, bg1, bg2, bg3,
                                                     bl1, bl2, bl3, out, ws);
    gather_kernel<<<256, 256, 0, stream>>>(idx, ws, pc, out);
}